// Round 11
// baseline (156.750 us; speedup 1.0000x reference)
//
#include <hip/hip_runtime.h>
#include <hip/hip_bf16.h>

// ---------------------------------------------------------------------------
// R18 = R17 + (a) 2 token-blocks per wave  (b) transposed Q/K projections
//       (c) early bf16 P-pack in softmax.
//   (a) 16384 -> 8192 waves. R13-R17 all equilibrate at ~12 resident
//       waves/CU with ~85% stall (wave-supply/latency equilibrium, not a
//       resource cap). Fatter waves double per-wave work and in-flight
//       loads (both blocks' x issued up front). NOT R11's serial
//       grid-stride: weights pre-packed (11-load prologue, shared), both
//       blocks' chains available to the scheduler for ILP.
//   (b) Q^T = Wq^T.h^T via MFMA16(fWq-as-A, ah-as-B): output lane=token
//       directly -> R16's 8 identity-transpose MFMAs + 16 packs deleted.
//       (Same A/B layout-sharing algebra as the verified transposed FFN.)
//   (c) P packed to bf16 inside the softmax loop -> f32 score tiles die
//       immediately (-20 live VGPR/block) so the 2-block variant fits
//       the (256,4) 128-VGPR budget without spill.
// Carried: ZERO LDS / ZERO barriers, no-max softmax (scores bounded),
// K=16 fragment composition, prep-packed weights, transposed FFN.
// Layouts (v_mfma_f32_16x16x16bf16_1k, verified R15-R17):
//   C/D: D[m=quad*4+reg][n=lane&15]
//   A:   A[m=lane&15][k=quad*4+j]   (word p = elems 2p(lo16), 2p+1(hi16))
//   B:   B[k=quad*4+j][n=lane&15]   (A and B share the lane/word mapping)
// ---------------------------------------------------------------------------

typedef __attribute__((ext_vector_type(4))) short bf4;   // 4 bf16 (2 VGPRs)
typedef __attribute__((ext_vector_type(4))) float f4;    // 4 fp32 (C/D frag)

union Frag2 { uint2 u2; uint u[2]; bf4 b; };
union F4U  { uint4 u4; float4 f; };

__device__ __forceinline__ uint packbf(float lo, float hi) {   // lo -> bits[15:0]
    union { __hip_bfloat162 h; uint u; } c;
    c.h = __float22bfloat162_rn(make_float2(lo, hi));
    return c.u;
}

// tanh-form gelu: u * sigma(2*sqrt(2/pi)*(u + 0.044715 u^3)), exp2 domain.
__device__ __forceinline__ float gelu_fast(float u) {
    float u2 = u * u;
    float t  = u * (-2.3022079f + -0.1029431f * u2);   // -2*log2e*c1*(1+c2 u^2)
    float e  = __builtin_amdgcn_exp2f(t);
    return u * __builtin_amdgcn_rcpf(1.f + e);
}

#define MFMA16(a, b, c) __builtin_amdgcn_mfma_f32_16x16x16bf16_1k(a, b, c, 0, 0, 0)

#define NWAVES 4
#define BLKW 2      // token-blocks per wave

// ws blob: per-lane 16 uint4 slots (256 B/lane, 16 KB):
//  0: {fWq, fWk}  1: {fWv, fW1a}  2: {fW1b, fW2a}  3: {fW2b, -}
//  4: ln1g[q4..+3] 5: ln1b[q4..+3] 6: ln2g[q4..+3] 7: ln2b[q4..+3]
//  8: b1[q4..+3]   9: b1[16+q4..+3] 10: b2[q4..+3]
#define WS_SLOTS 16

// K=16 bf16 fragment (2 words): element k=q*4+2p(+1), column n, row-major W.
// Serves as B[k][n] or A[m=n][k] (identical lane/word mapping).
__device__ __forceinline__ uint2 wfrag16(const float* __restrict__ W, int ld,
                                         int n, int q, float s) {
    uint2 w;
    w.x = packbf(W[(q*4+0)*ld+n]*s, W[(q*4+1)*ld+n]*s);
    w.y = packbf(W[(q*4+2)*ld+n]*s, W[(q*4+3)*ld+n]*s);
    return w;
}

__global__ __launch_bounds__(64, 1)
void prep_kernel(const float* __restrict__ Wk, const float* __restrict__ Wq,
                 const float* __restrict__ Wv,
                 const float* __restrict__ ln1g, const float* __restrict__ ln1b,
                 const float* __restrict__ ln2g, const float* __restrict__ ln2b,
                 const float* __restrict__ W1, const float* __restrict__ b1,
                 const float* __restrict__ W2, const float* __restrict__ b2,
                 uint4* __restrict__ ws)
{
    const int lane = threadIdx.x;
    const int c15  = lane & 15;
    const int quad = lane >> 4;
    const int quad4 = quad << 2;
    uint4* o = ws + lane * WS_SLOTS;
    // Wq folds 1/sqrt(16) and log2(e): scores land in log2 domain.
    uint2 fq  = wfrag16(Wq, 16, c15, quad, 0.25f*1.44269504f);
    uint2 fk  = wfrag16(Wk, 16, c15, quad, 1.0f);
    uint2 fv  = wfrag16(Wv, 16, c15, quad, 1.0f);
    uint2 f1a = wfrag16(W1, 32, c15,      quad, 1.0f);  // A[m=ff(c15)][k=ch]
    uint2 f1b = wfrag16(W1, 32, c15 + 16, quad, 1.0f);  // A[m=ff(16+c15)][k=ch]
    uint2 f2a = wfrag16(W2,        16, c15, quad, 1.0f); // A[m=ch][k=ff 0..15]
    uint2 f2b = wfrag16(W2 + 256,  16, c15, quad, 1.0f); // A[m=ch][k=ff 16..31]
    o[0] = make_uint4(fq.x, fq.y, fk.x, fk.y);
    o[1] = make_uint4(fv.x, fv.y, f1a.x, f1a.y);
    o[2] = make_uint4(f1b.x, f1b.y, f2a.x, f2a.y);
    o[3] = make_uint4(f2b.x, f2b.y, 0u, 0u);
    F4U a;
    a.f = *(const float4*)(ln1g + quad4); o[4]  = a.u4;
    a.f = *(const float4*)(ln1b + quad4); o[5]  = a.u4;
    a.f = *(const float4*)(ln2g + quad4); o[6]  = a.u4;
    a.f = *(const float4*)(ln2b + quad4); o[7]  = a.u4;
    a.f = *(const float4*)(b1 + quad4);      o[8]  = a.u4;
    a.f = *(const float4*)(b1 + 16 + quad4); o[9]  = a.u4;
    a.f = *(const float4*)(b2 + quad4);      o[10] = a.u4;
}

__global__ __launch_bounds__(64 * NWAVES, 4)
void tb_kernel(const float* __restrict__ x,
               const uint4* __restrict__ ws,
               float* __restrict__ out)
{
    const int tid  = threadIdx.x;
    const int lane = tid & 63;
    const int wid  = tid >> 6;
    const int c15  = lane & 15;
    const int quad = lane >> 4;
    const int quad4 = quad << 2;
    const size_t blk0 = ((size_t)blockIdx.x * NWAVES + wid) * BLKW;
    const f4 z4 = {0.f, 0.f, 0.f, 0.f};

    // ---- BOTH blocks' x issued up front (8 b128 in flight; feeds LN1 AND
    //      residual; main memory-level-parallelism win of 2-block waves)
    float4 xr[BLKW][4];
    #pragma unroll
    for (int b = 0; b < BLKW; ++b) {
        const float* xb = x + (blk0 + b) * 1024;
        #pragma unroll
        for (int qt = 0; qt < 4; ++qt)
            xr[b][qt] = *(const float4*)(xb + (size_t)(qt*16 + c15)*16 + quad4);
    }

    // ---- prologue: 11 b128 loads from the pre-packed blob (L2-hot)
    const uint4* wv = ws + lane * WS_SLOTS;
    uint4 s0 = wv[0], s1 = wv[1], s2 = wv[2], s3 = wv[3];
    Frag2 T;
    T.u[0]=s0.x; T.u[1]=s0.y; const bf4 fWq  = T.b;   // as A: Wq^T[m=ch_out][k=ch_in]
    T.u[0]=s0.z; T.u[1]=s0.w; const bf4 fWk  = T.b;   // as A: Wk^T
    T.u[0]=s1.x; T.u[1]=s1.y; const bf4 fWv  = T.b;   // as B: Wv[k=ch_in][n=ch_out]
    T.u[0]=s1.z; T.u[1]=s1.w; const bf4 fW1a = T.b;   // as A: A[m=ff(c15)][k=ch]
    T.u[0]=s2.x; T.u[1]=s2.y; const bf4 fW1b = T.b;   // as A: A[m=ff(16+c15)][k=ch]
    T.u[0]=s2.z; T.u[1]=s2.w; const bf4 fW2a = T.b;   // as A: A[m=ch][k=ff 0..15]
    T.u[0]=s3.x; T.u[1]=s3.y; const bf4 fW2b = T.b;   // as A: A[m=ch][k=ff 16..31]
    F4U fu;
    fu.u4 = wv[4];  const float4 g1  = fu.f;
    fu.u4 = wv[5];  const float4 b1l = fu.f;
    fu.u4 = wv[6];  const float4 g2  = fu.f;
    fu.u4 = wv[7];  const float4 b2l = fu.f;
    fu.u4 = wv[8];  const f4 cb0 = {fu.f.x, fu.f.y, fu.f.z, fu.f.w};  // b1[ff q4+r]
    fu.u4 = wv[9];  const f4 cb1 = {fu.f.x, fu.f.y, fu.f.z, fu.f.w};  // b1[16+q4+r]
    fu.u4 = wv[10]; const f4 cb2 = {fu.f.x, fu.f.y, fu.f.z, fu.f.w};  // b2[q4+r]

    // ---- LN1 both blocks (two-pass variance) -> A-frags in-lane
    bf4 ah[BLKW][4];
    #pragma unroll
    for (int b = 0; b < BLKW; ++b)
    #pragma unroll
    for (int qt = 0; qt < 4; ++qt) {
        float4 v = xr[b][qt];
        float s = v.x + v.y + v.z + v.w;
        s += __shfl_xor(s, 16); s += __shfl_xor(s, 32);
        float mu = s * 0.0625f;
        float d0 = v.x-mu, d1 = v.y-mu, d2 = v.z-mu, d3 = v.w-mu;
        float s2 = d0*d0 + d1*d1 + d2*d2 + d3*d3;
        s2 += __shfl_xor(s2, 16); s2 += __shfl_xor(s2, 32);
        float rstd = rsqrtf(s2 * 0.0625f + 1e-5f);
        float h0 = d0*rstd*g1.x + b1l.x;
        float h1 = d1*rstd*g1.y + b1l.y;
        float h2 = d2*rstd*g1.z + b1l.z;
        float h3 = d3*rstd*g1.w + b1l.w;
        Frag2 A; A.u[0] = packbf(h0, h1); A.u[1] = packbf(h2, h3);
        ah[b][qt] = A.b;   // A[m=tok(c15)][k=ch(quad*4+j)]; ALSO B[k=ch][n=tok]
    }

    // ---- per-block pipeline (unrolled; scheduler free to interleave blocks)
    #pragma unroll
    for (int b = 0; b < BLKW; ++b) {
        // -- projections (12 MFMA16): Q^T/K^T via TRANSPOSED proj
        //    tq = Wq^T.h^T: D[m=ch(quad4+r)][n=tok(c15)] -> lane=tok directly;
        //    in-lane pack => qb: B[k=ch][n=query], ka: A[m=key][k=ch].
        //    V normal: vc: D[m=tok][n=ch] -> pack => va: A[m=ch][k=key].
        bf4 qb[4], ka[4], va[4];
        #pragma unroll
        for (int mt = 0; mt < 4; ++mt) {
            f4 tq = MFMA16(fWq, ah[b][mt], z4);
            f4 tk = MFMA16(fWk, ah[b][mt], z4);
            f4 vc = MFMA16(ah[b][mt], fWv, z4);
            Frag2 Qb, Ka, V_;
            Qb.u[0] = packbf(tq[0], tq[1]); Qb.u[1] = packbf(tq[2], tq[3]);
            Ka.u[0] = packbf(tk[0], tk[1]); Ka.u[1] = packbf(tk[2], tk[3]);
            V_.u[0] = packbf(vc[0], vc[1]); V_.u[1] = packbf(vc[2], vc[3]);
            qb[mt] = Qb.b; ka[mt] = Ka.b; va[mt] = V_.b;
        }

        // -- S^T + softmax fused per query column (10 MFMA16, no-max,
        //    log2-domain scores, EARLY bf16 pack: f32 tiles die immediately)
        uint2 pk[4][4];            // pk[kt][qt]; only kt<=qt written/read
        float linv[4];
        #pragma unroll
        for (int qt = 0; qt < 4; ++qt) {
            f4 stc[4];
            #pragma unroll
            for (int kt = 0; kt <= qt; ++kt)
                stc[kt] = MFMA16(ka[kt], qb[qt], z4);
            #pragma unroll
            for (int r = 0; r < 4; ++r)     // causal mask on diagonal tile
                stc[qt][r] = (quad4 + r <= c15) ? stc[qt][r] : -1e30f;
            float l = 0.f;
            #pragma unroll
            for (int kt = 0; kt <= qt; ++kt) {
                float p0 = __builtin_amdgcn_exp2f(stc[kt][0]);
                float p1 = __builtin_amdgcn_exp2f(stc[kt][1]);
                float p2 = __builtin_amdgcn_exp2f(stc[kt][2]);
                float p3 = __builtin_amdgcn_exp2f(stc[kt][3]);
                l += (p0 + p1) + (p2 + p3);
                pk[kt][qt] = make_uint2(packbf(p0, p1), packbf(p2, p3));
            }
            l += __shfl_xor(l, 16);
            l += __shfl_xor(l, 32);
            linv[qt] = __builtin_amdgcn_rcpf(l);   // l in [1,64]
        }

        // -- PV (10 MFMA16) + residual + LN2 + FFN1 (8 MFMA16)
        float x2v[4][4];
        f4 uu0[4], uu1[4];
        #pragma unroll
        for (int qt = 0; qt < 4; ++qt) {
            f4 acc = z4;
            #pragma unroll
            for (int kt = 0; kt <= qt; ++kt) {
                Frag2 P_;              // B[k=key(quad*4+j)][n=query(c15)]
                P_.u2 = pk[kt][qt];
                acc = MFMA16(va[kt], P_.b, acc);
            }
            const float li = linv[qt]; // D[m=ch=quad4+r][n=query=c15]
            x2v[qt][0] = xr[b][qt].x + acc[0]*li;
            x2v[qt][1] = xr[b][qt].y + acc[1]*li;
            x2v[qt][2] = xr[b][qt].z + acc[2]*li;
            x2v[qt][3] = xr[b][qt].w + acc[3]*li;
            // LN2 (two-pass, cross-quad butterfly)
            float s = x2v[qt][0]+x2v[qt][1]+x2v[qt][2]+x2v[qt][3];
            s += __shfl_xor(s, 16); s += __shfl_xor(s, 32);
            float mu = s * 0.0625f;
            float d0 = x2v[qt][0]-mu, d1 = x2v[qt][1]-mu,
                  d2 = x2v[qt][2]-mu, d3 = x2v[qt][3]-mu;
            float s2 = d0*d0 + d1*d1 + d2*d2 + d3*d3;
            s2 += __shfl_xor(s2, 16); s2 += __shfl_xor(s2, 32);
            float rstd = rsqrtf(s2 * 0.0625f + 1e-5f);
            float h0 = d0*rstd*g2.x + b2l.x;
            float h1 = d1*rstd*g2.y + b2l.y;
            float h2 = d2*rstd*g2.z + b2l.z;
            float h3 = d3*rstd*g2.w + b2l.w;
            Frag2 Hb;                  // B[k=ch(quad*4+j)][n=tok(c15)]
            Hb.u[0] = packbf(h0, h1); Hb.u[1] = packbf(h2, h3);
            // FFN1 transposed: U^T = W1^T.h2^T   D[m=ff=quad4+r][n=tok]
            uu0[qt] = MFMA16(fW1a, Hb.b, cb0);
            uu1[qt] = MFMA16(fW1b, Hb.b, cb1);
        }

        // -- gelu + FFN2 (8 MFMA16) -> direct store layout
        float* ob = out + (blk0 + b) * 1024;
        #pragma unroll
        for (int qt = 0; qt < 4; ++qt) {
            Frag2 Pa, Pb;              // B[k=ff(quad*4+j)][n=tok(c15)]
            Pa.u[0] = packbf(gelu_fast(uu0[qt][0]), gelu_fast(uu0[qt][1]));
            Pa.u[1] = packbf(gelu_fast(uu0[qt][2]), gelu_fast(uu0[qt][3]));
            Pb.u[0] = packbf(gelu_fast(uu1[qt][0]), gelu_fast(uu1[qt][1]));
            Pb.u[1] = packbf(gelu_fast(uu1[qt][2]), gelu_fast(uu1[qt][3]));
            f4 fo = MFMA16(fW2a, Pa.b, cb2);
            fo = MFMA16(fW2b, Pb.b, fo);   // D[m=ch=quad4+r][n=tok=qt*16+c15]
            float4 o;
            o.x = x2v[qt][0] + fo[0];
            o.y = x2v[qt][1] + fo[1];
            o.z = x2v[qt][2] + fo[2];
            o.w = x2v[qt][3] + fo[3];
            *(float4*)(ob + (size_t)(qt*16 + c15)*16 + quad4) = o;
        }
    }
}

extern "C" void kernel_launch(void* const* d_in, const int* in_sizes, int n_in,
                              void* d_out, int out_size, void* d_ws, size_t ws_size,
                              hipStream_t stream) {
    const float* x     = (const float*)d_in[0];
    const float* Wk    = (const float*)d_in[1];
    const float* Wq    = (const float*)d_in[2];
    const float* Wv    = (const float*)d_in[3];
    const float* ln1_g = (const float*)d_in[4];
    const float* ln1_b = (const float*)d_in[5];
    const float* ln2_g = (const float*)d_in[6];
    const float* ln2_b = (const float*)d_in[7];
    const float* W1    = (const float*)d_in[8];
    const float* b1    = (const float*)d_in[9];
    const float* W2    = (const float*)d_in[10];
    const float* b2    = (const float*)d_in[11];
    float* out = (float*)d_out;
    uint4* ws = (uint4*)d_ws;

    prep_kernel<<<1, 64, 0, stream>>>(Wk, Wq, Wv, ln1_g, ln1_b, ln2_g, ln2_b,
                                      W1, b1, W2, b2, ws);
    const int n_blocks = in_sizes[0] / (64 * 16);       // 16384
    const int nwg = n_blocks / (NWAVES * BLKW);         // 2048 wgs x 256 thr
    tb_kernel<<<nwg, 64 * NWAVES, 0, stream>>>(x, ws, out);
}